// Round 4
// baseline (357.193 us; speedup 1.0000x reference)
//
#include <hip/hip_runtime.h>
#include <hip/hip_bf16.h>

// LabelWiseMLC: out[b,l] = sigmoid(dot(doc_rep[b,l,:], W[l,:]) + bias[l])
// B=128, L=512, I=1024, fp32. Memory-bound: doc = 256 MiB streamed once;
// HBM floor ~43 us.
//
// R4: LDS-staged per-wave pipeline to break the VGPR-bounded MLP ceiling.
// Each wave owns one label l and WPB=16 batch rows. doc rows (4 KiB) are
// DMA'd into a per-wave 2x4KiB LDS double buffer via global_load_lds
// (width 16, no VGPR round-trip). Manual s_waitcnt vmcnt(4) keeps the next
// row's 4 loads in flight across consumption (never drain to 0 - the m97
// lesson). No __syncthreads: each wave stages and consumes its own rows.
// In-flight bytes/CU: 16 waves x 4-8 KiB = 64-128 KiB >> the ~9 KiB
// latency-BW product -> HBM-saturating regardless of loaded latency.
// W[l] lives in 16 VGPRs, loaded once per wave (16 MiB total, L2-served).
// LDS 32 KiB/block -> 5 blocks/CU possible; grid 1024 blocks = 4/CU resident.

#define B_DIM 128
#define L_DIM 512
#define I_DIM 1024
#define WPB 16            // batch rows per wave
#define WAVES_PER_BLOCK 4

typedef float vfloat4 __attribute__((ext_vector_type(4)));

// Stage one 4 KiB doc row into LDS: 4 instrs x (64 lanes x 16 B).
// HW semantics: each lane stores to lds_base + lane*16 (wave-uniform base).
__device__ __forceinline__ void async_row_load(const float* g, float* l,
                                               int lane) {
#pragma unroll
    for (int k = 0; k < 4; ++k) {
        __builtin_amdgcn_global_load_lds(
            (const __attribute__((address_space(1))) void*)(g + k * 256 + lane * 4),
            (__attribute__((address_space(3))) void*)(l + k * 256),
            16, 0, 0);
    }
}

__global__ __launch_bounds__(256) void labelwise_mlc_kernel(
    const float* __restrict__ doc,   // (B, L, I)
    const float* __restrict__ W,     // (L, I)
    const float* __restrict__ bias,  // (L,)
    float* __restrict__ out)         // (B, L)
{
    __shared__ float smem[WAVES_PER_BLOCK][2][I_DIM];  // 32 KiB

    const int wid  = threadIdx.x >> 6;
    const int lane = threadIdx.x & 63;
    const int gw   = blockIdx.x * WAVES_PER_BLOCK + wid;  // 0..4095
    const int l    = gw & (L_DIM - 1);
    const int b0   = (gw >> 9) * WPB;

    const size_t rstride = (size_t)L_DIM * I_DIM;  // floats between rows b,b+1
    const float* rowbase = doc + ((size_t)b0 * L_DIM + l) * I_DIM;

    float* buf0 = &smem[wid][0][0];
    float* buf1 = &smem[wid][1][0];

    // Kick off rows 0 and 1 before touching W (loads overlap).
    async_row_load(rowbase, buf0, lane);
    async_row_load(rowbase + rstride, buf1, lane);

    // W[l] fragment: lane i holds float4s at elements {4i+256k}, k=0..3
    const vfloat4* __restrict__ wp = (const vfloat4*)(W + (size_t)l * I_DIM);
    vfloat4 w[4];
#pragma unroll
    for (int k = 0; k < 4; ++k) w[k] = wp[lane + 64 * k];
    const float bl = bias[l];

    for (int j = 0; j < WPB; ++j) {
        // Row j's 4 DMA loads are the oldest outstanding; allow row j+1's 4
        // to stay in flight. (vmcnt retires oldest-first; W/bias loads were
        // issued before row 0 so they're covered at j=0.)
        if (j < WPB - 1) __builtin_amdgcn_s_waitcnt(0xF74);  // vmcnt(4)
        else             __builtin_amdgcn_s_waitcnt(0xF70);  // vmcnt(0)

        const float* lb = (j & 1) ? buf1 : buf0;
        float acc = 0.0f;
#pragma unroll
        for (int k = 0; k < 4; ++k) {
            const vfloat4 d = ((const vfloat4*)lb)[lane + 64 * k];
            acc = fmaf(d.x, w[k].x, acc);
            acc = fmaf(d.y, w[k].y, acc);
            acc = fmaf(d.z, w[k].z, acc);
            acc = fmaf(d.w, w[k].w, acc);
        }

        // WAR guard: ds_reads of this buffer must have fully returned before
        // the DMA below may overwrite it.
        __builtin_amdgcn_s_waitcnt(0xC07F);  // lgkmcnt(0), vmcnt/exp no-wait
        if (j + 2 < WPB)
            async_row_load(rowbase + (size_t)(j + 2) * rstride,
                           (j & 1) ? buf1 : buf0, lane);

        // 64-lane reduction + epilogue
#pragma unroll
        for (int off = 32; off > 0; off >>= 1)
            acc += __shfl_down(acc, off, 64);
        if (lane == 0) {
            const float v = acc + bl;
            out[(size_t)(b0 + j) * L_DIM + l] = 1.0f / (1.0f + __expf(-v));
        }
    }
}

extern "C" void kernel_launch(void* const* d_in, const int* in_sizes, int n_in,
                              void* d_out, int out_size, void* d_ws, size_t ws_size,
                              hipStream_t stream) {
    const float* doc  = (const float*)d_in[0];  // (128, 512, 1024)
    const float* W    = (const float*)d_in[1];  // (512, 1024)
    const float* bias = (const float*)d_in[2];  // (512,)
    float* out = (float*)d_out;                 // (128, 512)

    // 4096 waves: 512 labels x 8 row-groups (16 rows each); 4 waves/block
    const int blocks = (L_DIM * (B_DIM / WPB)) / WAVES_PER_BLOCK;  // 1024
    labelwise_mlc_kernel<<<blocks, 256, 0, stream>>>(doc, W, bias, out);
}

// Round 5
// 357.107 us; speedup vs baseline: 1.0002x; 1.0002x over previous
//
#include <hip/hip_runtime.h>
#include <hip/hip_bf16.h>

// LabelWiseMLC: out[b,l] = sigmoid(dot(doc_rep[b,l,:], W[l,:]) + bias[l])
// B=128, L=512, I=1024, all fp32. Memory-bound: doc is 256 MiB streamed once;
// HBM floor ~43 us for the kernel slice (total dur_us is harness-dominated:
// ~160 us d_ws poison fill + ~80 us doc restore copy visible in rocprof).
//
// R5 = R3 structure (best so far, 332 us) with nontemporal dropped:
// label-stationary waves, each owns one label l and WPB=8 batch rows.
// W[l] (4 KiB) loaded ONCE into 16 VGPRs, reused across 8 dot products.
// Plain doc loads: the harness's doc-restore copy runs right before the
// kernel, so doc may be Infinity-Cache-resident; nt loads would skip that.
// R4's LDS-DMA pipeline regressed (357 us) -> register MLP (8 KiB/wave in
// flight with unroll 2) already saturates; reverted.
// 8192 waves = 2048 blocks x 4 waves -> 8 blocks/CU, full 32 waves/CU.

#define B_DIM 128
#define L_DIM 512
#define I_DIM 1024
#define WPB 8  // batch rows per wave

typedef float vfloat4 __attribute__((ext_vector_type(4)));

__global__ __launch_bounds__(256) void labelwise_mlc_kernel(
    const float* __restrict__ doc,   // (B, L, I)
    const float* __restrict__ W,     // (L, I)
    const float* __restrict__ bias,  // (L,)
    float* __restrict__ out)         // (B, L)
{
    const int wave = (blockIdx.x * 256 + threadIdx.x) >> 6;  // 0..8191
    const int lane = threadIdx.x & 63;
    const int l  = wave & (L_DIM - 1);          // label index
    const int b0 = (wave >> 9) * WPB;           // starting batch row

    // W[l] fragment: lane i holds float4s at {i, 64+i, 128+i, 192+i}
    const vfloat4* __restrict__ wp = (const vfloat4*)(W + (size_t)l * I_DIM);
    vfloat4 w[4];
#pragma unroll
    for (int k = 0; k < 4; ++k) w[k] = wp[lane + 64 * k];
    const float bl = bias[l];

#pragma unroll 2
    for (int j = 0; j < WPB; ++j) {
        const int b = b0 + j;
        const vfloat4* __restrict__ dp =
            (const vfloat4*)(doc + ((size_t)b * L_DIM + l) * I_DIM);
        float acc = 0.0f;
#pragma unroll
        for (int k = 0; k < 4; ++k) {
            const vfloat4 d = dp[lane + 64 * k];
            acc = fmaf(d.x, w[k].x, acc);
            acc = fmaf(d.y, w[k].y, acc);
            acc = fmaf(d.z, w[k].z, acc);
            acc = fmaf(d.w, w[k].w, acc);
        }
        // 64-lane wave reduction
#pragma unroll
        for (int off = 32; off > 0; off >>= 1)
            acc += __shfl_down(acc, off, 64);
        if (lane == 0) {
            const float v = acc + bl;
            out[(size_t)b * L_DIM + l] = 1.0f / (1.0f + __expf(-v));
        }
    }
}

extern "C" void kernel_launch(void* const* d_in, const int* in_sizes, int n_in,
                              void* d_out, int out_size, void* d_ws, size_t ws_size,
                              hipStream_t stream) {
    const float* doc  = (const float*)d_in[0];  // (128, 512, 1024)
    const float* W    = (const float*)d_in[1];  // (512, 1024)
    const float* bias = (const float*)d_in[2];  // (512,)
    float* out = (float*)d_out;                 // (128, 512)

    // 8192 waves total: 512 labels x 16 wave-groups (8 batch rows each)
    const int blocks = (L_DIM * (B_DIM / WPB)) / 4;  // 2048
    labelwise_mlc_kernel<<<blocks, 256, 0, stream>>>(doc, W, bias, out);
}

// Round 6
// 333.853 us; speedup vs baseline: 1.0699x; 1.0697x over previous
//
#include <hip/hip_runtime.h>
#include <hip/hip_bf16.h>

// LabelWiseMLC: out[b,l] = sigmoid(dot(doc_rep[b,l,:], W[l,:]) + bias[l])
// B=128, L=512, I=1024, all fp32. Memory-bound: doc is 256 MiB streamed once;
// kernel HBM floor ~43 us. Total dur_us is harness-dominated (~160 us d_ws
// poison fill + doc restore copy dominate the rocprof top-5).
//
// R6 = exact R3 re-bench (reproducibility test). R3(nt)=332, R5(no nt)=357,
// R4(LDS DMA)=357. Either nt is worth 25 us or the harness noise floor is
// +/-25 us (R4 and R5 tying at 357.1/357.2 hints at noise). Single-variable:
// none - this IS R3's source.
//
// Structure: label-stationary waves; each wave owns one label l and WPB=8
// batch rows. W[l] (4 KiB) loaded ONCE into 16 VGPRs, reused 8x. doc loads
// nontemporal (streamed, zero reuse). 8192 waves = 2048 blocks x 4 waves.

#define B_DIM 128
#define L_DIM 512
#define I_DIM 1024
#define WPB 8  // batch rows per wave

typedef float vfloat4 __attribute__((ext_vector_type(4)));

__global__ __launch_bounds__(256) void labelwise_mlc_kernel(
    const float* __restrict__ doc,   // (B, L, I)
    const float* __restrict__ W,     // (L, I)
    const float* __restrict__ bias,  // (L,)
    float* __restrict__ out)         // (B, L)
{
    const int wave = (blockIdx.x * 256 + threadIdx.x) >> 6;  // 0..8191
    const int lane = threadIdx.x & 63;
    const int l  = wave & (L_DIM - 1);          // label index
    const int b0 = (wave >> 9) * WPB;           // starting batch row

    // W[l] fragment: lane i holds float4s at {i, 64+i, 128+i, 192+i}
    const vfloat4* __restrict__ wp = (const vfloat4*)(W + (size_t)l * I_DIM);
    vfloat4 w[4];
#pragma unroll
    for (int k = 0; k < 4; ++k) w[k] = wp[lane + 64 * k];
    const float bl = bias[l];

#pragma unroll 2
    for (int j = 0; j < WPB; ++j) {
        const int b = b0 + j;
        const vfloat4* __restrict__ dp =
            (const vfloat4*)(doc + ((size_t)b * L_DIM + l) * I_DIM);
        float acc = 0.0f;
#pragma unroll
        for (int k = 0; k < 4; ++k) {
            const vfloat4 d = __builtin_nontemporal_load(dp + lane + 64 * k);
            acc = fmaf(d.x, w[k].x, acc);
            acc = fmaf(d.y, w[k].y, acc);
            acc = fmaf(d.z, w[k].z, acc);
            acc = fmaf(d.w, w[k].w, acc);
        }
        // 64-lane wave reduction
#pragma unroll
        for (int off = 32; off > 0; off >>= 1)
            acc += __shfl_down(acc, off, 64);
        if (lane == 0) {
            const float v = acc + bl;
            out[(size_t)b * L_DIM + l] = 1.0f / (1.0f + __expf(-v));
        }
    }
}

extern "C" void kernel_launch(void* const* d_in, const int* in_sizes, int n_in,
                              void* d_out, int out_size, void* d_ws, size_t ws_size,
                              hipStream_t stream) {
    const float* doc  = (const float*)d_in[0];  // (128, 512, 1024)
    const float* W    = (const float*)d_in[1];  // (512, 1024)
    const float* bias = (const float*)d_in[2];  // (512,)
    float* out = (float*)d_out;                 // (128, 512)

    // 8192 waves total: 512 labels x 16 wave-groups (8 batch rows each)
    const int blocks = (L_DIM * (B_DIM / WPB)) / 4;  // 2048
    labelwise_mlc_kernel<<<blocks, 256, 0, stream>>>(doc, W, bias, out);
}